// Round 1
// baseline (1080.296 us; speedup 1.0000x reference)
//
#include <hip/hip_runtime.h>
#include <hip/hip_bf16.h>
#include <math.h>

#define V_NODES 262144
#define NGRAPH  4096
#define FD      256
#define TSTEPS  2

typedef unsigned short u16;

__device__ __forceinline__ float bf2f(u16 u) {
  union { unsigned int i; float f; } x; x.i = ((unsigned int)u) << 16; return x.f;
}
__device__ __forceinline__ u16 f2bf(float f) {
  union { unsigned int i; float f; } x; x.f = f;
  unsigned int r = x.i + 0x7FFFu + ((x.i >> 16) & 1u);
  return (u16)(r >> 16);
}
__device__ __forceinline__ float softplus2(float x) {
  // logaddexp(x,0) - ln2, stable
  return fmaxf(x, 0.0f) + log1pf(__expf(-fabsf(x))) - 0.69314718056f;
}

// ---- K0: segment boundaries. start[g] = first v with seg[v] >= g; start[G] = V.
__global__ void k_bounds(const int* __restrict__ seg, int* __restrict__ start) {
  int v = blockIdx.x * blockDim.x + threadIdx.x;
  if (v >= V_NODES) return;
  int s = seg[v];
  if (v == 0) {
    for (int g = 0; g <= s; ++g) start[g] = 0;
  } else {
    int p = seg[v - 1];
    for (int g = p + 1; g <= s; ++g) start[g] = v;
  }
  if (v == V_NODES - 1) {
    for (int g = s + 1; g <= NGRAPH; ++g) start[g] = V_NODES;
  }
}

// ---- K1: initial g_feats = segment_sum(node_feats); optional bf16 copy of nodes.
template <int USEBF>
__global__ void k_segsum(const float* __restrict__ nf, const int* __restrict__ start,
                         float* __restrict__ gf, u16* __restrict__ nbf) {
  const int g = blockIdx.x, f = threadIdx.x;
  const int s = start[g], e = start[g + 1];
  float acc = 0.0f;
  for (int v = s; v < e; ++v) {
    float x = nf[(size_t)v * FD + f];
    acc += x;
    if (USEBF) nbf[(size_t)v * FD + f] = f2bf(x);
  }
  gf[(size_t)g * FD + f] = acc;
}

// ---- K2: per-graph logits + softplus2 + segment softmax + weighted node sum.
// One block (256 thr) per graph. wns[g,f] = sum_v a_v * n_v[f].
template <int USEBF>
__global__ void k_attn(const float* __restrict__ nf, const u16* __restrict__ nbf,
                       const int* __restrict__ start, const float* __restrict__ gf,
                       const float* __restrict__ lw, const float* __restrict__ lbp,
                       float* __restrict__ zbuf, float* __restrict__ wns) {
  __shared__ float lws[2 * FD];
  __shared__ float sred[4];
  const int g = blockIdx.x, tid = threadIdx.x;
  const int lane = tid & 63, wave = tid >> 6;
  lws[tid] = lw[tid];
  lws[FD + tid] = lw[FD + tid];
  const int s = start[g], e = start[g + 1];
  const float lb = lbp[0];

  // c_g = sum_f relu(gf[g,f]) * lwA[f]
  float cv = fmaxf(gf[(size_t)g * FD + tid], 0.0f) * lw[tid];
#pragma unroll
  for (int off = 32; off > 0; off >>= 1) cv += __shfl_down(cv, off, 64);
  if (lane == 0) sred[wave] = cv;
  __syncthreads();
  const float c = sred[0] + sred[1] + sred[2] + sred[3];

  // stage 1: z_v = softplus2(c + dot(n_v, lwB) + b); wave-per-node
  const float w0 = lws[FD + lane * 4 + 0], w1 = lws[FD + lane * 4 + 1],
              w2 = lws[FD + lane * 4 + 2], w3 = lws[FD + lane * 4 + 3];
  float maxz = -1e30f;
  for (int v = s + wave; v < e; v += 4) {
    float dot;
    if (USEBF) {
      const ushort4 u = *(const ushort4*)(nbf + (size_t)v * FD + lane * 4);
      dot = fmaf(bf2f(u.x), w0, fmaf(bf2f(u.y), w1, fmaf(bf2f(u.z), w2, bf2f(u.w) * w3)));
    } else {
      const float4 x = *(const float4*)(nf + (size_t)v * FD + lane * 4);
      dot = fmaf(x.x, w0, fmaf(x.y, w1, fmaf(x.z, w2, x.w * w3)));
    }
#pragma unroll
    for (int off = 32; off > 0; off >>= 1) dot += __shfl_down(dot, off, 64);
    if (lane == 0) {
      float z = softplus2(c + dot + lb);
      zbuf[v] = z;
      maxz = fmaxf(maxz, z);
    }
  }
  __syncthreads();                // c/lws reads done; zbuf stage-1 writes drained
  if (lane == 0) sred[wave] = maxz;
  __syncthreads();
  const float zmax = fmaxf(fmaxf(sred[0], sred[1]), fmaxf(sred[2], sred[3]));

  // stage 2: e_v = exp(z - zmax), denom
  float dloc = 0.0f;
  for (int v = s + tid; v < e; v += 256) {
    float ez = __expf(zbuf[v] - zmax);
    zbuf[v] = ez;
    dloc += ez;
  }
#pragma unroll
  for (int off = 32; off > 0; off >>= 1) dloc += __shfl_down(dloc, off, 64);
  __syncthreads();                // zmax reads done; zbuf stage-2 writes drained
  if (lane == 0) sred[wave] = dloc;
  __syncthreads();
  const float denom = sred[0] + sred[1] + sred[2] + sred[3];

  // stage 3: wns[g,f] = (sum_v e_v * n_v[f]) / denom
  float acc = 0.0f;
  for (int v = s; v < e; ++v) {
    const float ez = zbuf[v];
    const float x = USEBF ? bf2f(nbf[(size_t)v * FD + tid]) : nf[(size_t)v * FD + tid];
    acc = fmaf(ez, x, acc);
  }
  wns[(size_t)g * FD + tid] = (e > s) ? (acc / denom) : 0.0f;
}

// ---- transpose [768,256] -> [256,768] (for GRU weights: gi = x @ W^T)
__global__ void k_transpose768(const float* __restrict__ src, float* __restrict__ dst) {
  __shared__ float tile[32][33];
  const int bx = blockIdx.x;  // k-tile: 256/32 = 8
  const int by = blockIdx.y;  // j-tile: 768/32 = 24
  const int tx = threadIdx.x, ty = threadIdx.y;  // 32 x 8
#pragma unroll
  for (int i = 0; i < 32; i += 8)
    tile[ty + i][tx] = src[(size_t)(by * 32 + ty + i) * 256 + bx * 32 + tx];
  __syncthreads();
#pragma unroll
  for (int i = 0; i < 32; i += 8)
    dst[(size_t)(bx * 32 + ty + i) * 768 + by * 32 + tx] = tile[tx][ty + i];
}

// ---- row-tile GEMM: Y[M,N] = act(X[M,256] @ W[256,N] + B[N]); 32 rows/block.
// ACT: 0 = none, 1 = elu
template <int ACT>
__global__ void k_gemm_rowtile(const float* __restrict__ X, const float* __restrict__ W,
                               const float* __restrict__ B, float* __restrict__ Y, int N) {
  const int ROWS = 32;
  __shared__ float xs[ROWS * 260];
  const int tid = threadIdx.x;
  const int cb = blockIdx.x;  // column block (N/256)
  const int rb = blockIdx.y;  // row block (M/32)
  const int col = cb * 256 + tid;
  const float* Xb = X + (size_t)rb * ROWS * 256;
#pragma unroll 4
  for (int r = 0; r < ROWS; ++r) xs[r * 260 + tid] = Xb[(size_t)r * 256 + tid];
  __syncthreads();
  float acc[ROWS];
  const float bias = B[col];
#pragma unroll
  for (int r = 0; r < ROWS; ++r) acc[r] = bias;
  for (int k = 0; k < 256; k += 4) {
    const float wv0 = W[(size_t)(k + 0) * N + col];
    const float wv1 = W[(size_t)(k + 1) * N + col];
    const float wv2 = W[(size_t)(k + 2) * N + col];
    const float wv3 = W[(size_t)(k + 3) * N + col];
#pragma unroll
    for (int r = 0; r < ROWS; ++r) {
      const float4 xv = *(const float4*)&xs[r * 260 + k];
      acc[r] = fmaf(xv.x, wv0, fmaf(xv.y, wv1, fmaf(xv.z, wv2, fmaf(xv.w, wv3, acc[r]))));
    }
  }
  float* Yb = Y + (size_t)rb * ROWS * N;
#pragma unroll 4
  for (int r = 0; r < ROWS; ++r) {
    float v = acc[r];
    if (ACT == 1) v = (v > 0.0f) ? v : expm1f(v);
    Yb[(size_t)r * N + col] = v;
  }
}

// ---- GRU elementwise combine (in-place update of h)
__global__ void k_gru(const float* __restrict__ gi, const float* __restrict__ gh,
                      float* __restrict__ h) {
  const int g = blockIdx.x, f = threadIdx.x;
  const float* gir = gi + (size_t)g * 768;
  const float* ghr = gh + (size_t)g * 768;
  const float ir = gir[f], iz = gir[256 + f], in_ = gir[512 + f];
  const float hr = ghr[f], hz = ghr[256 + f], hn = ghr[512 + f];
  const float r = 1.0f / (1.0f + __expf(-(ir + hr)));
  const float z = 1.0f / (1.0f + __expf(-(iz + hz)));
  const float n = tanhf(in_ + r * hn);
  const size_t idx = (size_t)g * 256 + f;
  const float hv = h[idx];
  h[idx] = (1.0f - z) * n + z * hv;
}

extern "C" void kernel_launch(void* const* d_in, const int* in_sizes, int n_in,
                              void* d_out, int out_size, void* d_ws, size_t ws_size,
                              hipStream_t stream) {
  const float* node    = (const float*)d_in[0];
  const int*   seg     = (const int*)d_in[1];
  // d_in[2] = num_graphs (device scalar) — G fixed at 4096 for this problem
  const float* logit_w = (const float*)d_in[3];  // [T, 512]
  const float* logit_b = (const float*)d_in[4];  // [T, 1]
  const float* proj_w  = (const float*)d_in[5];  // [T, 256, 256]
  const float* proj_b  = (const float*)d_in[6];  // [T, 256]
  const float* w_ih    = (const float*)d_in[7];  // [T, 768, 256]
  const float* w_hh    = (const float*)d_in[8];  // [T, 768, 256]
  const float* b_ih    = (const float*)d_in[9];  // [T, 768]
  const float* b_hh    = (const float*)d_in[10]; // [T, 768]
  float* gfeats = (float*)d_out;                 // [4096, 256] — working h and final output

  char* p = (char*)d_ws;
  int* start  = (int*)p;    p += (((NGRAPH + 1) * sizeof(int)) + 255) & ~(size_t)255;
  float* zbuf = (float*)p;  p += (size_t)V_NODES * 4;
  float* wns  = (float*)p;  p += (size_t)NGRAPH * FD * 4;
  float* ctx  = (float*)p;  p += (size_t)NGRAPH * FD * 4;
  float* gi   = (float*)p;  p += (size_t)NGRAPH * 768 * 4;
  float* gh   = (float*)p;  p += (size_t)NGRAPH * 768 * 4;
  float* wT   = (float*)p;  p += (size_t)4 * 256 * 768 * 4;  // [t][ih,hh][256][768]
  u16* nbf    = (u16*)p;
  const size_t need_bf = (size_t)(p - (char*)d_ws) + (size_t)V_NODES * FD * sizeof(u16);
  const bool usebf = (ws_size >= need_bf);

  k_bounds<<<dim3(V_NODES / 256), dim3(256), 0, stream>>>(seg, start);
  if (usebf) k_segsum<1><<<dim3(NGRAPH), dim3(256), 0, stream>>>(node, start, gfeats, nbf);
  else       k_segsum<0><<<dim3(NGRAPH), dim3(256), 0, stream>>>(node, start, gfeats, nbf);

  for (int t = 0; t < TSTEPS; ++t) {
    k_transpose768<<<dim3(8, 24), dim3(32, 8), 0, stream>>>(
        w_ih + (size_t)t * 768 * 256, wT + (size_t)(t * 2 + 0) * 256 * 768);
    k_transpose768<<<dim3(8, 24), dim3(32, 8), 0, stream>>>(
        w_hh + (size_t)t * 768 * 256, wT + (size_t)(t * 2 + 1) * 256 * 768);
  }

  for (int t = 0; t < TSTEPS; ++t) {
    const float* lw = logit_w + (size_t)t * 2 * FD;
    if (usebf)
      k_attn<1><<<dim3(NGRAPH), dim3(256), 0, stream>>>(node, nbf, start, gfeats, lw,
                                                        logit_b + t, zbuf, wns);
    else
      k_attn<0><<<dim3(NGRAPH), dim3(256), 0, stream>>>(node, nbf, start, gfeats, lw,
                                                        logit_b + t, zbuf, wns);
    // context = elu(wns @ proj_w + proj_b)
    k_gemm_rowtile<1><<<dim3(1, NGRAPH / 32), dim3(256), 0, stream>>>(
        wns, proj_w + (size_t)t * FD * FD, proj_b + (size_t)t * FD, ctx, 256);
    // gi = ctx @ w_ih^T + b_ih ; gh = h @ w_hh^T + b_hh
    k_gemm_rowtile<0><<<dim3(3, NGRAPH / 32), dim3(256), 0, stream>>>(
        ctx, wT + (size_t)(t * 2 + 0) * 256 * 768, b_ih + (size_t)t * 768, gi, 768);
    k_gemm_rowtile<0><<<dim3(3, NGRAPH / 32), dim3(256), 0, stream>>>(
        gfeats, wT + (size_t)(t * 2 + 1) * 256 * 768, b_hh + (size_t)t * 768, gh, 768);
    k_gru<<<dim3(NGRAPH), dim3(256), 0, stream>>>(gi, gh, gfeats);
  }
}

// Round 2
// 718.343 us; speedup vs baseline: 1.5039x; 1.5039x over previous
//
#include <hip/hip_runtime.h>
#include <hip/hip_bf16.h>
#include <math.h>

#define V_NODES 262144
#define NGRAPH  4096
#define FD      256
#define TSTEPS  2

typedef unsigned short u16;
typedef __attribute__((ext_vector_type(8))) short short8;
typedef __attribute__((ext_vector_type(4))) float f32x4;

__device__ __forceinline__ float bf2f(u16 u) {
  union { unsigned int i; float f; } x; x.i = ((unsigned int)u) << 16; return x.f;
}
__device__ __forceinline__ u16 f2bf(float f) {
  union { unsigned int i; float f; } x; x.f = f;
  unsigned int r = x.i + 0x7FFFu + ((x.i >> 16) & 1u);
  return (u16)(r >> 16);
}
__device__ __forceinline__ float softplus2(float x) {
  return fmaxf(x, 0.0f) + log1pf(__expf(-fabsf(x))) - 0.69314718056f;
}

// ---- K0: segment boundaries. start[g] = first v with seg[v] >= g; start[G] = V.
__global__ void k_bounds(const int* __restrict__ seg, int* __restrict__ start) {
  int v = blockIdx.x * blockDim.x + threadIdx.x;
  if (v >= V_NODES) return;
  int s = seg[v];
  if (v == 0) {
    for (int g = 0; g <= s; ++g) start[g] = 0;
  } else {
    int p = seg[v - 1];
    for (int g = p + 1; g <= s; ++g) start[g] = v;
  }
  if (v == V_NODES - 1) {
    for (int g = s + 1; g <= NGRAPH; ++g) start[g] = V_NODES;
  }
}

// ---- K1: g_feats = segment_sum(nodes); emit bf16 node copy + h hi/lo split.
// float4 loads; 4 row-quads reduced via LDS.
__global__ __launch_bounds__(256) void k_segsum(
    const float* __restrict__ nf, const int* __restrict__ start,
    float* __restrict__ gf, u16* __restrict__ nbf,
    u16* __restrict__ hhi, u16* __restrict__ hlo) {
  __shared__ float red[4][FD];
  const int g = blockIdx.x, tid = threadIdx.x;
  const int q = tid >> 6, l = tid & 63;
  const int s = start[g], e = start[g + 1];
  float a0 = 0.f, a1 = 0.f, a2 = 0.f, a3 = 0.f;
  const float4* nfv = (const float4*)nf;
  ushort4* nbv = (ushort4*)nbf;
  for (int v = s + q; v < e; v += 4) {
    const float4 x = nfv[(size_t)v * 64 + l];
    a0 += x.x; a1 += x.y; a2 += x.z; a3 += x.w;
    ushort4 ub;
    ub.x = f2bf(x.x); ub.y = f2bf(x.y); ub.z = f2bf(x.z); ub.w = f2bf(x.w);
    nbv[(size_t)v * 64 + l] = ub;
  }
  red[q][l * 4 + 0] = a0; red[q][l * 4 + 1] = a1;
  red[q][l * 4 + 2] = a2; red[q][l * 4 + 3] = a3;
  __syncthreads();
  const float sum = red[0][tid] + red[1][tid] + red[2][tid] + red[3][tid];
  const size_t idx = (size_t)g * FD + tid;
  gf[idx] = sum;
  const u16 hi = f2bf(sum);
  hhi[idx] = hi;
  hlo[idx] = f2bf(sum - bf2f(hi));
}

// ---- K2: fused attention: logits + online softmax + weighted node sum, ONE nbf pass.
__global__ __launch_bounds__(256) void k_attn(
    const u16* __restrict__ nbf, const int* __restrict__ start,
    const float* __restrict__ gf, const float* __restrict__ lw,
    const float* __restrict__ lbp, u16* __restrict__ wnsbf) {
  __shared__ float lwB[FD];
  __shared__ float sred[4];
  __shared__ float accred[4][FD];
  __shared__ float mred[4], lred[4];
  const int g = blockIdx.x, tid = threadIdx.x;
  const int lane = tid & 63, wave = tid >> 6;
  lwB[tid] = lw[FD + tid];
  const int s = start[g], e = start[g + 1];
  const float lb = lbp[0];

  // c = sum_f relu(gf[g,f]) * lwA[f]
  float cv = fmaxf(gf[(size_t)g * FD + tid], 0.0f) * lw[tid];
#pragma unroll
  for (int off = 1; off < 64; off <<= 1) cv += __shfl_xor(cv, off, 64);
  if (lane == 0) sred[wave] = cv;
  __syncthreads();
  const float c = sred[0] + sred[1] + sred[2] + sred[3];
  const float w0 = lwB[lane * 4 + 0], w1 = lwB[lane * 4 + 1],
              w2 = lwB[lane * 4 + 2], w3 = lwB[lane * 4 + 3];

  // wave-per-node: z, then online-softmax accumulate of e*n (n kept in regs)
  float m = -1e30f, lsum = 0.f;
  float a0 = 0.f, a1 = 0.f, a2 = 0.f, a3 = 0.f;
  const ushort4* nbv = (const ushort4*)nbf;
  for (int v = s + wave; v < e; v += 4) {
    const ushort4 u = nbv[(size_t)v * 64 + lane];
    const float x0 = bf2f(u.x), x1 = bf2f(u.y), x2 = bf2f(u.z), x3 = bf2f(u.w);
    float d = fmaf(x0, w0, fmaf(x1, w1, fmaf(x2, w2, x3 * w3)));
#pragma unroll
    for (int off = 1; off < 64; off <<= 1) d += __shfl_xor(d, off, 64);
    const float z = softplus2(c + d + lb);
    const float mn = fmaxf(m, z);
    const float sc = __expf(m - mn);
    const float ez = __expf(z - mn);
    lsum = fmaf(lsum, sc, ez);
    a0 = fmaf(a0, sc, ez * x0);
    a1 = fmaf(a1, sc, ez * x1);
    a2 = fmaf(a2, sc, ez * x2);
    a3 = fmaf(a3, sc, ez * x3);
    m = mn;
  }
  if (lane == 0) mred[wave] = m;
  __syncthreads();
  const float M = fmaxf(fmaxf(mred[0], mred[1]), fmaxf(mred[2], mred[3]));
  const float fac = __expf(m - M);  // 0 for waves with no nodes (m=-1e30)
  accred[wave][lane * 4 + 0] = a0 * fac;
  accred[wave][lane * 4 + 1] = a1 * fac;
  accred[wave][lane * 4 + 2] = a2 * fac;
  accred[wave][lane * 4 + 3] = a3 * fac;
  if (lane == 0) lred[wave] = lsum * fac;
  __syncthreads();
  const float num = accred[0][tid] + accred[1][tid] + accred[2][tid] + accred[3][tid];
  const float den = lred[0] + lred[1] + lred[2] + lred[3];
  wnsbf[(size_t)g * FD + tid] = f2bf((e > s) ? (num / den) : 0.0f);
}

// ---- fp32 -> bf16 elementwise (vectorized)
__global__ void k_cvt(const float* __restrict__ src, u16* __restrict__ dst, int n4) {
  const int i = blockIdx.x * 256 + threadIdx.x;
  if (i >= n4) return;
  const float4 x = ((const float4*)src)[i];
  ushort4 u;
  u.x = f2bf(x.x); u.y = f2bf(x.y); u.z = f2bf(x.z); u.w = f2bf(x.w);
  ((ushort4*)dst)[i] = u;
}

// ---- fp32 -> bf16 hi/lo split elementwise
__global__ void k_cvt_split(const float* __restrict__ src, u16* __restrict__ hi,
                            u16* __restrict__ lo, int n) {
  const int i = blockIdx.x * 256 + threadIdx.x;
  if (i >= n) return;
  const float x = src[i];
  const u16 h = f2bf(x);
  hi[i] = h;
  lo[i] = f2bf(x - bf2f(h));
}

// ---- proj_w [k][n] -> bf16 [n][k] transpose (per t)
__global__ void k_cvt_t(const float* __restrict__ src, u16* __restrict__ dst) {
  __shared__ float tile[32][33];
  const int t = blockIdx.z;
  const float* S = src + (size_t)t * FD * FD;
  u16* D = dst + (size_t)t * FD * FD;
  const int bx = blockIdx.x, by = blockIdx.y;
  const int tx = threadIdx.x, ty = threadIdx.y;  // 32 x 8
#pragma unroll
  for (int i = 0; i < 32; i += 8)
    tile[ty + i][tx] = S[(size_t)(by * 32 + ty + i) * FD + bx * 32 + tx];
  __syncthreads();
#pragma unroll
  for (int i = 0; i < 32; i += 8)
    D[(size_t)(bx * 32 + ty + i) * FD + by * 32 + tx] = f2bf(tile[tx][ty + i]);
}

// ---- MFMA GEMM: Y[M,N] = act(X[M,256] @ W[N,256]^T + bias[N])
// 16x16x32 bf16; one wave per 16x16 tile; A: m=lane&15,k=q*8+j; B: n=lane&15 same k;
// D: col=lane&15, row=q*4+reg (verified m89/m91).
// SPLIT: 0 = Xhi*Whi; 1 = +Xlo*Whi; 2 = +Xhi*Wlo.
template <int ACT, int OUTBF, int SPLIT>
__global__ __launch_bounds__(256) void k_wgemm(
    const u16* __restrict__ Xhi, const u16* __restrict__ Xlo,
    const u16* __restrict__ Whi, const u16* __restrict__ Wlo,
    const float* __restrict__ bias, float* __restrict__ Yf,
    u16* __restrict__ Ybf, int N) {
  const int tid = threadIdx.x, lane = tid & 63, wave = tid >> 6;
  const int mt = blockIdx.y * 4 + wave;
  const int nt = blockIdx.x;
  const int r = lane & 15, q = lane >> 4;
  const u16* xp = Xhi + (size_t)(mt * 16 + r) * FD + q * 8;
  const u16* wp = Whi + (size_t)(nt * 16 + r) * FD + q * 8;
  f32x4 acc = {0.f, 0.f, 0.f, 0.f};
#pragma unroll
  for (int kt = 0; kt < 8; ++kt) {
    const short8 a = *(const short8*)(xp + kt * 32);
    const short8 b = *(const short8*)(wp + kt * 32);
    acc = __builtin_amdgcn_mfma_f32_16x16x32_bf16(a, b, acc, 0, 0, 0);
  }
  if (SPLIT >= 1) {
    const u16* xp2 = Xlo + (size_t)(mt * 16 + r) * FD + q * 8;
#pragma unroll
    for (int kt = 0; kt < 8; ++kt) {
      const short8 a = *(const short8*)(xp2 + kt * 32);
      const short8 b = *(const short8*)(wp + kt * 32);
      acc = __builtin_amdgcn_mfma_f32_16x16x32_bf16(a, b, acc, 0, 0, 0);
    }
  }
  if (SPLIT >= 2) {
    const u16* wp2 = Wlo + (size_t)(nt * 16 + r) * FD + q * 8;
#pragma unroll
    for (int kt = 0; kt < 8; ++kt) {
      const short8 a = *(const short8*)(xp + kt * 32);
      const short8 b = *(const short8*)(wp2 + kt * 32);
      acc = __builtin_amdgcn_mfma_f32_16x16x32_bf16(a, b, acc, 0, 0, 0);
    }
  }
  const int gcol = nt * 16 + r;
  const float bs = bias[gcol];
  const int row0 = mt * 16 + q * 4;
#pragma unroll
  for (int i = 0; i < 4; ++i) {
    float v = acc[i] + bs;
    if (ACT == 1) v = (v > 0.0f) ? v : expm1f(v);
    if (OUTBF) Ybf[(size_t)(row0 + i) * N + gcol] = f2bf(v);
    else       Yf[(size_t)(row0 + i) * N + gcol] = v;
  }
}

// ---- GRU combine (in-place h update) + bf16 hi/lo emit for next step
__global__ __launch_bounds__(256) void k_gru(
    const float* __restrict__ gi, const float* __restrict__ gh,
    float* __restrict__ h, u16* __restrict__ hhi, u16* __restrict__ hlo) {
  const int g = blockIdx.x, f = threadIdx.x;
  const float* gir = gi + (size_t)g * 768;
  const float* ghr = gh + (size_t)g * 768;
  const float ir = gir[f], iz = gir[256 + f], in_ = gir[512 + f];
  const float hr = ghr[f], hz = ghr[256 + f], hn = ghr[512 + f];
  const float r = 1.0f / (1.0f + __expf(-(ir + hr)));
  const float z = 1.0f / (1.0f + __expf(-(iz + hz)));
  const float n = tanhf(in_ + r * hn);
  const size_t idx = (size_t)g * FD + f;
  const float hv = h[idx];
  const float hnew = (1.0f - z) * n + z * hv;
  h[idx] = hnew;
  const u16 hb = f2bf(hnew);
  hhi[idx] = hb;
  hlo[idx] = f2bf(hnew - bf2f(hb));
}

extern "C" void kernel_launch(void* const* d_in, const int* in_sizes, int n_in,
                              void* d_out, int out_size, void* d_ws, size_t ws_size,
                              hipStream_t stream) {
  const float* node    = (const float*)d_in[0];
  const int*   seg     = (const int*)d_in[1];
  const float* logit_w = (const float*)d_in[3];  // [T, 512]
  const float* logit_b = (const float*)d_in[4];  // [T, 1]
  const float* proj_w  = (const float*)d_in[5];  // [T, 256, 256]
  const float* proj_b  = (const float*)d_in[6];  // [T, 256]
  const float* w_ih    = (const float*)d_in[7];  // [T, 768, 256] = [N][K]
  const float* w_hh    = (const float*)d_in[8];  // [T, 768, 256] = [N][K]
  const float* b_ih    = (const float*)d_in[9];  // [T, 768]
  const float* b_hh    = (const float*)d_in[10]; // [T, 768]
  float* gfeats = (float*)d_out;                 // [4096, 256] working h + output

  char* p = (char*)d_ws;
  int* start   = (int*)p;  p += (((NGRAPH + 1) * sizeof(int)) + 255) & ~(size_t)255;
  u16* nbf     = (u16*)p;  p += (size_t)V_NODES * FD * 2;
  u16* hhi     = (u16*)p;  p += (size_t)NGRAPH * FD * 2;
  u16* hlo     = (u16*)p;  p += (size_t)NGRAPH * FD * 2;
  u16* wnsbf   = (u16*)p;  p += (size_t)NGRAPH * FD * 2;
  u16* ctxbf   = (u16*)p;  p += (size_t)NGRAPH * FD * 2;
  float* gi    = (float*)p; p += (size_t)NGRAPH * 768 * 4;
  float* gh    = (float*)p; p += (size_t)NGRAPH * 768 * 4;
  u16* wihbf   = (u16*)p;  p += (size_t)TSTEPS * 768 * FD * 2;
  u16* whhbf   = (u16*)p;  p += (size_t)TSTEPS * 768 * FD * 2;
  u16* whhlo   = (u16*)p;  p += (size_t)TSTEPS * 768 * FD * 2;
  u16* pwtbf   = (u16*)p;  p += (size_t)TSTEPS * FD * FD * 2;
  (void)ws_size; (void)in_sizes; (void)n_in; (void)out_size;

  k_bounds<<<dim3(V_NODES / 256), dim3(256), 0, stream>>>(seg, start);
  k_segsum<<<dim3(NGRAPH), dim3(256), 0, stream>>>(node, start, gfeats, nbf, hhi, hlo);

  const int nw = TSTEPS * 768 * FD;
  k_cvt<<<dim3(nw / 4 / 256), dim3(256), 0, stream>>>(w_ih, wihbf, nw / 4);
  k_cvt_split<<<dim3(nw / 256), dim3(256), 0, stream>>>(w_hh, whhbf, whhlo, nw);
  k_cvt_t<<<dim3(8, 8, TSTEPS), dim3(32, 8), 0, stream>>>(proj_w, pwtbf);

  for (int t = 0; t < TSTEPS; ++t) {
    k_attn<<<dim3(NGRAPH), dim3(256), 0, stream>>>(
        nbf, start, gfeats, logit_w + (size_t)t * 2 * FD, logit_b + t, wnsbf);
    // ctx(bf16) = elu(wns @ proj_w + proj_b)
    k_wgemm<1, 1, 0><<<dim3(FD / 16, NGRAPH / 64), dim3(256), 0, stream>>>(
        wnsbf, nullptr, pwtbf + (size_t)t * FD * FD, nullptr,
        proj_b + (size_t)t * FD, nullptr, ctxbf, FD);
    // gi = ctx @ w_ih^T + b_ih
    k_wgemm<0, 0, 0><<<dim3(768 / 16, NGRAPH / 64), dim3(256), 0, stream>>>(
        ctxbf, nullptr, wihbf + (size_t)t * 768 * FD, nullptr,
        b_ih + (size_t)t * 768, gi, nullptr, 768);
    // gh = h @ w_hh^T + b_hh  (split-bf16 X and W for precision)
    k_wgemm<0, 0, 2><<<dim3(768 / 16, NGRAPH / 64), dim3(256), 0, stream>>>(
        hhi, hlo, whhbf + (size_t)t * 768 * FD, whhlo + (size_t)t * 768 * FD,
        b_hh + (size_t)t * 768, gh, nullptr, 768);
    k_gru<<<dim3(NGRAPH), dim3(256), 0, stream>>>(gi, gh, gfeats, hhi, hlo);
  }
}

// Round 3
// 643.523 us; speedup vs baseline: 1.6787x; 1.1163x over previous
//
#include <hip/hip_runtime.h>
#include <hip/hip_bf16.h>
#include <math.h>

#define V_NODES 262144
#define NGRAPH  4096
#define FD      256
#define TSTEPS  2

typedef unsigned short u16;
typedef __attribute__((ext_vector_type(8))) short short8;
typedef __attribute__((ext_vector_type(4))) float f32x4;

__device__ __forceinline__ float bf2f(u16 u) {
  union { unsigned int i; float f; } x; x.i = ((unsigned int)u) << 16; return x.f;
}
__device__ __forceinline__ u16 f2bf(float f) {
  union { unsigned int i; float f; } x; x.f = f;
  unsigned int r = x.i + 0x7FFFu + ((x.i >> 16) & 1u);
  return (u16)(r >> 16);
}
__device__ __forceinline__ float softplus2(float x) {
  return fmaxf(x, 0.0f) + log1pf(__expf(-fabsf(x))) - 0.69314718056f;
}

// ---- K0: segment boundaries. start[g] = first v with seg[v] >= g; start[G] = V.
__global__ void k_bounds(const int* __restrict__ seg, int* __restrict__ start) {
  int v = blockIdx.x * blockDim.x + threadIdx.x;
  if (v >= V_NODES) return;
  int s = seg[v];
  if (v == 0) {
    for (int g = 0; g <= s; ++g) start[g] = 0;
  } else {
    int p = seg[v - 1];
    for (int g = p + 1; g <= s; ++g) start[g] = v;
  }
  if (v == V_NODES - 1) {
    for (int g = s + 1; g <= NGRAPH; ++g) start[g] = V_NODES;
  }
}

// ---- K1: ONE fp32 pass over nodes: segment-sum -> h0 (+bf16 hi/lo), bf16 node
// copy, and the two logit dots d_t[v] = dot(n_v, lwB_t) precomputed.
__global__ __launch_bounds__(256) void k_pass1(
    const float* __restrict__ nf, const int* __restrict__ start,
    const float* __restrict__ logit_w,
    float* __restrict__ gf, u16* __restrict__ nbf,
    u16* __restrict__ hhi, u16* __restrict__ hlo,
    float* __restrict__ d0, float* __restrict__ d1) {
  __shared__ float red[4][FD];
  const int g = blockIdx.x, tid = threadIdx.x;
  const int wv = tid >> 6, l = tid & 63;
  const int s = start[g], e = start[g + 1];
  // lwB_t for features 4l..4l+3
  const float4 wA = ((const float4*)(logit_w + FD))[l];          // t=0, lwB
  const float4 wB = ((const float4*)(logit_w + 512 + FD))[l];    // t=1, lwB
  float a0 = 0.f, a1 = 0.f, a2 = 0.f, a3 = 0.f;
  const float4* nfv = (const float4*)nf;
  ushort4* nbv = (ushort4*)nbf;
  for (int v = s + wv; v < e; v += 4) {
    const float4 x = nfv[(size_t)v * 64 + l];
    a0 += x.x; a1 += x.y; a2 += x.z; a3 += x.w;
    ushort4 ub;
    ub.x = f2bf(x.x); ub.y = f2bf(x.y); ub.z = f2bf(x.z); ub.w = f2bf(x.w);
    nbv[(size_t)v * 64 + l] = ub;
    float dA = fmaf(x.x, wA.x, fmaf(x.y, wA.y, fmaf(x.z, wA.z, x.w * wA.w)));
    float dB = fmaf(x.x, wB.x, fmaf(x.y, wB.y, fmaf(x.z, wB.z, x.w * wB.w)));
#pragma unroll
    for (int off = 1; off < 64; off <<= 1) {
      dA += __shfl_xor(dA, off, 64);
      dB += __shfl_xor(dB, off, 64);
    }
    if (l == 0) { d0[v] = dA; d1[v] = dB; }
  }
  red[wv][l * 4 + 0] = a0; red[wv][l * 4 + 1] = a1;
  red[wv][l * 4 + 2] = a2; red[wv][l * 4 + 3] = a3;
  __syncthreads();
  const float sum = red[0][tid] + red[1][tid] + red[2][tid] + red[3][tid];
  const size_t idx = (size_t)g * FD + tid;
  gf[idx] = sum;
  const u16 hi = f2bf(sum);
  hhi[idx] = hi;
  hlo[idx] = f2bf(sum - bf2f(hi));
}

// ---- K2: per-graph softmax weights from precomputed dots. One WAVE per graph.
// Writes abuf[v] = exp(z_v - zmax) and den[g] = sum.
__global__ __launch_bounds__(256) void k_attnw(
    const int* __restrict__ start, const float* __restrict__ gf,
    const float* __restrict__ lwA, const float* __restrict__ lbp,
    const float* __restrict__ dt, float* __restrict__ abuf,
    float* __restrict__ den) {
  const int tid = threadIdx.x, lane = tid & 63, wv = tid >> 6;
  const int g = blockIdx.x * 4 + wv;
  const int s = start[g], e = start[g + 1];
  const float lb = lbp[0];
  // c = sum_f relu(gf[g,f]) * lwA[f]
  const float4 hv = ((const float4*)(gf + (size_t)g * FD))[lane];
  const float4 wa = ((const float4*)lwA)[lane];
  float c = fmaf(fmaxf(hv.x, 0.f), wa.x, fmaf(fmaxf(hv.y, 0.f), wa.y,
            fmaf(fmaxf(hv.z, 0.f), wa.z, fmaxf(hv.w, 0.f) * wa.w)));
#pragma unroll
  for (int off = 1; off < 64; off <<= 1) c += __shfl_xor(c, off, 64);
  // pass A: z, running max
  float m = -1e30f;
  for (int v = s + lane; v < e; v += 64) {
    const float z = softplus2(c + dt[v] + lb);
    abuf[v] = z;
    m = fmaxf(m, z);
  }
#pragma unroll
  for (int off = 1; off < 64; off <<= 1) m = fmaxf(m, __shfl_xor(m, off, 64));
  // pass B: e = exp(z - M), sum
  float lsum = 0.f;
  for (int v = s + lane; v < e; v += 64) {
    const float ez = __expf(abuf[v] - m);
    abuf[v] = ez;
    lsum += ez;
  }
#pragma unroll
  for (int off = 1; off < 64; off <<= 1) lsum += __shfl_xor(lsum, off, 64);
  if (lane == 0) den[g] = lsum;
}

// ---- K3: streaming weighted node sum: wns[g,f] = (sum_v e_v n_v[f]) / den[g].
// 16 B/lane bf16 loads; wave covers 2 nodes; no transcendentals in loop.
__global__ __launch_bounds__(256) void k_wsum(
    const u16* __restrict__ nbf, const int* __restrict__ start,
    const float* __restrict__ abuf, const float* __restrict__ den,
    u16* __restrict__ wnsbf) {
  __shared__ float red[4][FD];
  const int g = blockIdx.x, tid = threadIdx.x;
  const int wv = tid >> 6, lane = tid & 63;
  const int half = lane >> 5, fl = lane & 31;  // feature-lane: 8 feats each
  const int s = start[g], e = start[g + 1];
  float acc[8];
#pragma unroll
  for (int j = 0; j < 8; ++j) acc[j] = 0.f;
  for (int v0 = s + 2 * wv + half; v0 < e; v0 += 8) {
    const uint4 u = ((const uint4*)(nbf + (size_t)v0 * FD))[fl];
    const float ev = abuf[v0];
    acc[0] = fmaf(ev, bf2f((u16)(u.x & 0xffff)), acc[0]);
    acc[1] = fmaf(ev, bf2f((u16)(u.x >> 16)),    acc[1]);
    acc[2] = fmaf(ev, bf2f((u16)(u.y & 0xffff)), acc[2]);
    acc[3] = fmaf(ev, bf2f((u16)(u.y >> 16)),    acc[3]);
    acc[4] = fmaf(ev, bf2f((u16)(u.z & 0xffff)), acc[4]);
    acc[5] = fmaf(ev, bf2f((u16)(u.z >> 16)),    acc[5]);
    acc[6] = fmaf(ev, bf2f((u16)(u.w & 0xffff)), acc[6]);
    acc[7] = fmaf(ev, bf2f((u16)(u.w >> 16)),    acc[7]);
  }
#pragma unroll
  for (int j = 0; j < 8; ++j) acc[j] += __shfl_xor(acc[j], 32, 64);
  if (half == 0) {
#pragma unroll
    for (int j = 0; j < 8; ++j) red[wv][fl * 8 + j] = acc[j];
  }
  __syncthreads();
  const float num = red[0][tid] + red[1][tid] + red[2][tid] + red[3][tid];
  const float dv = den[g];
  wnsbf[(size_t)g * FD + tid] = f2bf((e > s) ? (num / dv) : 0.0f);
}

// ---- fp32 -> bf16 elementwise (vectorized)
__global__ void k_cvt(const float* __restrict__ src, u16* __restrict__ dst, int n4) {
  const int i = blockIdx.x * 256 + threadIdx.x;
  if (i >= n4) return;
  const float4 x = ((const float4*)src)[i];
  ushort4 u;
  u.x = f2bf(x.x); u.y = f2bf(x.y); u.z = f2bf(x.z); u.w = f2bf(x.w);
  ((ushort4*)dst)[i] = u;
}

// ---- fp32 -> bf16 hi/lo split elementwise
__global__ void k_cvt_split(const float* __restrict__ src, u16* __restrict__ hi,
                            u16* __restrict__ lo, int n) {
  const int i = blockIdx.x * 256 + threadIdx.x;
  if (i >= n) return;
  const float x = src[i];
  const u16 h = f2bf(x);
  hi[i] = h;
  lo[i] = f2bf(x - bf2f(h));
}

// ---- proj_w [k][n] -> bf16 [n][k] transpose (per t)
__global__ void k_cvt_t(const float* __restrict__ src, u16* __restrict__ dst) {
  __shared__ float tile[32][33];
  const int t = blockIdx.z;
  const float* S = src + (size_t)t * FD * FD;
  u16* D = dst + (size_t)t * FD * FD;
  const int bx = blockIdx.x, by = blockIdx.y;
  const int tx = threadIdx.x, ty = threadIdx.y;  // 32 x 8
#pragma unroll
  for (int i = 0; i < 32; i += 8)
    tile[ty + i][tx] = S[(size_t)(by * 32 + ty + i) * FD + bx * 32 + tx];
  __syncthreads();
#pragma unroll
  for (int i = 0; i < 32; i += 8)
    D[(size_t)(bx * 32 + ty + i) * FD + by * 32 + tx] = f2bf(tile[tx][ty + i]);
}

// ---- MFMA GEMM: Y[M,N] = act(X[M,256] @ W[N,256]^T + bias[N])
// 16x16x32 bf16; wave per 16x16 tile. SPLIT: 0=hi*hi; 2=+Xlo*Whi+Xhi*Wlo.
template <int ACT, int OUTBF, int SPLIT>
__global__ __launch_bounds__(256) void k_wgemm(
    const u16* __restrict__ Xhi, const u16* __restrict__ Xlo,
    const u16* __restrict__ Whi, const u16* __restrict__ Wlo,
    const float* __restrict__ bias, float* __restrict__ Yf,
    u16* __restrict__ Ybf, int N) {
  const int tid = threadIdx.x, lane = tid & 63, wave = tid >> 6;
  const int mt = blockIdx.y * 4 + wave;
  const int nt = blockIdx.x;
  const int r = lane & 15, q = lane >> 4;
  const u16* xp = Xhi + (size_t)(mt * 16 + r) * FD + q * 8;
  const u16* wp = Whi + (size_t)(nt * 16 + r) * FD + q * 8;
  f32x4 acc = {0.f, 0.f, 0.f, 0.f};
#pragma unroll
  for (int kt = 0; kt < 8; ++kt) {
    const short8 a = *(const short8*)(xp + kt * 32);
    const short8 b = *(const short8*)(wp + kt * 32);
    acc = __builtin_amdgcn_mfma_f32_16x16x32_bf16(a, b, acc, 0, 0, 0);
  }
  if (SPLIT >= 1) {
    const u16* xp2 = Xlo + (size_t)(mt * 16 + r) * FD + q * 8;
#pragma unroll
    for (int kt = 0; kt < 8; ++kt) {
      const short8 a = *(const short8*)(xp2 + kt * 32);
      const short8 b = *(const short8*)(wp + kt * 32);
      acc = __builtin_amdgcn_mfma_f32_16x16x32_bf16(a, b, acc, 0, 0, 0);
    }
  }
  if (SPLIT >= 2) {
    const u16* wp2 = Wlo + (size_t)(nt * 16 + r) * FD + q * 8;
#pragma unroll
    for (int kt = 0; kt < 8; ++kt) {
      const short8 a = *(const short8*)(xp + kt * 32);
      const short8 b = *(const short8*)(wp2 + kt * 32);
      acc = __builtin_amdgcn_mfma_f32_16x16x32_bf16(a, b, acc, 0, 0, 0);
    }
  }
  const int gcol = nt * 16 + r;
  const float bs = bias[gcol];
  const int row0 = mt * 16 + q * 4;
#pragma unroll
  for (int i = 0; i < 4; ++i) {
    float v = acc[i] + bs;
    if (ACT == 1) v = (v > 0.0f) ? v : expm1f(v);
    if (OUTBF) Ybf[(size_t)(row0 + i) * N + gcol] = f2bf(v);
    else       Yf[(size_t)(row0 + i) * N + gcol] = v;
  }
}

// ---- GRU combine (in-place h update) + bf16 hi/lo emit for next step
__global__ __launch_bounds__(256) void k_gru(
    const float* __restrict__ gi, const float* __restrict__ gh,
    float* __restrict__ h, u16* __restrict__ hhi, u16* __restrict__ hlo) {
  const int g = blockIdx.x, f = threadIdx.x;
  const float* gir = gi + (size_t)g * 768;
  const float* ghr = gh + (size_t)g * 768;
  const float ir = gir[f], iz = gir[256 + f], in_ = gir[512 + f];
  const float hr = ghr[f], hz = ghr[256 + f], hn = ghr[512 + f];
  const float r = 1.0f / (1.0f + __expf(-(ir + hr)));
  const float z = 1.0f / (1.0f + __expf(-(iz + hz)));
  const float n = tanhf(in_ + r * hn);
  const size_t idx = (size_t)g * FD + f;
  const float hv = h[idx];
  const float hnew = (1.0f - z) * n + z * hv;
  h[idx] = hnew;
  const u16 hb = f2bf(hnew);
  hhi[idx] = hb;
  hlo[idx] = f2bf(hnew - bf2f(hb));
}

extern "C" void kernel_launch(void* const* d_in, const int* in_sizes, int n_in,
                              void* d_out, int out_size, void* d_ws, size_t ws_size,
                              hipStream_t stream) {
  const float* node    = (const float*)d_in[0];
  const int*   seg     = (const int*)d_in[1];
  const float* logit_w = (const float*)d_in[3];  // [T, 512]
  const float* logit_b = (const float*)d_in[4];  // [T, 1]
  const float* proj_w  = (const float*)d_in[5];  // [T, 256, 256]
  const float* proj_b  = (const float*)d_in[6];  // [T, 256]
  const float* w_ih    = (const float*)d_in[7];  // [T, 768, 256] = [N][K]
  const float* w_hh    = (const float*)d_in[8];  // [T, 768, 256] = [N][K]
  const float* b_ih    = (const float*)d_in[9];  // [T, 768]
  const float* b_hh    = (const float*)d_in[10]; // [T, 768]
  float* gfeats = (float*)d_out;                 // [4096, 256] working h + output

  char* p = (char*)d_ws;
  int* start   = (int*)p;  p += (((NGRAPH + 1) * sizeof(int)) + 255) & ~(size_t)255;
  u16* nbf     = (u16*)p;  p += (size_t)V_NODES * FD * 2;
  float* d0    = (float*)p; p += (size_t)V_NODES * 4;
  float* d1    = (float*)p; p += (size_t)V_NODES * 4;
  float* abuf  = (float*)p; p += (size_t)V_NODES * 4;
  float* den   = (float*)p; p += (size_t)NGRAPH * 4;
  u16* hhi     = (u16*)p;  p += (size_t)NGRAPH * FD * 2;
  u16* hlo     = (u16*)p;  p += (size_t)NGRAPH * FD * 2;
  u16* wnsbf   = (u16*)p;  p += (size_t)NGRAPH * FD * 2;
  u16* ctxbf   = (u16*)p;  p += (size_t)NGRAPH * FD * 2;
  float* gi    = (float*)p; p += (size_t)NGRAPH * 768 * 4;
  float* gh    = (float*)p; p += (size_t)NGRAPH * 768 * 4;
  u16* wihbf   = (u16*)p;  p += (size_t)TSTEPS * 768 * FD * 2;
  u16* whhbf   = (u16*)p;  p += (size_t)TSTEPS * 768 * FD * 2;
  u16* whhlo   = (u16*)p;  p += (size_t)TSTEPS * 768 * FD * 2;
  u16* pwtbf   = (u16*)p;  p += (size_t)TSTEPS * FD * FD * 2;
  (void)ws_size; (void)in_sizes; (void)n_in; (void)out_size;

  k_bounds<<<dim3(V_NODES / 256), dim3(256), 0, stream>>>(seg, start);
  k_pass1<<<dim3(NGRAPH), dim3(256), 0, stream>>>(node, start, logit_w,
                                                  gfeats, nbf, hhi, hlo, d0, d1);

  const int nw = TSTEPS * 768 * FD;
  k_cvt<<<dim3(nw / 4 / 256), dim3(256), 0, stream>>>(w_ih, wihbf, nw / 4);
  k_cvt_split<<<dim3(nw / 256), dim3(256), 0, stream>>>(w_hh, whhbf, whhlo, nw);
  k_cvt_t<<<dim3(8, 8, TSTEPS), dim3(32, 8), 0, stream>>>(proj_w, pwtbf);

  for (int t = 0; t < TSTEPS; ++t) {
    k_attnw<<<dim3(NGRAPH / 4), dim3(256), 0, stream>>>(
        start, gfeats, logit_w + (size_t)t * 512, logit_b + t,
        (t == 0) ? d0 : d1, abuf, den);
    k_wsum<<<dim3(NGRAPH), dim3(256), 0, stream>>>(nbf, start, abuf, den, wnsbf);
    // ctx(bf16) = elu(wns @ proj_w + proj_b)
    k_wgemm<1, 1, 0><<<dim3(FD / 16, NGRAPH / 64), dim3(256), 0, stream>>>(
        wnsbf, nullptr, pwtbf + (size_t)t * FD * FD, nullptr,
        proj_b + (size_t)t * FD, nullptr, ctxbf, FD);
    // gi = ctx @ w_ih^T + b_ih
    k_wgemm<0, 0, 0><<<dim3(768 / 16, NGRAPH / 64), dim3(256), 0, stream>>>(
        ctxbf, nullptr, wihbf + (size_t)t * 768 * FD, nullptr,
        b_ih + (size_t)t * 768, gi, nullptr, 768);
    // gh = h @ w_hh^T + b_hh  (split-bf16 X and W for precision)
    k_wgemm<0, 0, 2><<<dim3(768 / 16, NGRAPH / 64), dim3(256), 0, stream>>>(
        hhi, hlo, whhbf + (size_t)t * 768 * FD, whhlo + (size_t)t * 768 * FD,
        b_hh + (size_t)t * 768, gh, nullptr, 768);
    k_gru<<<dim3(NGRAPH), dim3(256), 0, stream>>>(gi, gh, gfeats, hhi, hlo);
  }
}